// Round 18
// baseline (144.025 us; speedup 1.0000x reference)
//
#include <hip/hip_runtime.h>
#include <stdint.h>

#define DDIM   1024
#define M_TOT  8192
#define N_ROWS 4096
#define KT     16              // 1024 / BK=64 (fp8: 64 B per row per K-tile)
#define NQUAD  8320            // 2080 cells (128x128, J<=I) x 4 quadrants (64x64)
#define SLOTW  8192            // per-wave slot: A 4KB + B 4KB
#define LDS_TOTAL (2 * SLOTW)  // 16 KB per 1-wave block -> 10 waves/CU

typedef __attribute__((ext_vector_type(4))) float f32x4;
typedef __attribute__((ext_vector_type(2))) long i64x2;

__device__ __forceinline__ void gload_lds16(const void* g, void* l) {
  __builtin_amdgcn_global_load_lds(
      (const __attribute__((address_space(1))) uint32_t*)g,
      (__attribute__((address_space(3))) uint32_t*)l, 16, 0, 0);
}

// ---------- kernel 1: row-normalize, emit PERMUTED fp8 z, per-row pos/align partials ----------
// z8 row = 1024 fp8 bytes. Within each 64-B K-group, 8-byte chunks stored in order
// [c0,c4,c1,c5,c2,c6,c3,c7] so one ds_read_b128 in kgemm yields both K=32 MFMA frags
// per lane (R13-proven). Also zeroes denom/uacc (folded memset).
__global__ __launch_bounds__(256) void knorm(const float* __restrict__ p1,
                                             const float* __restrict__ p2,
                                             unsigned char* __restrict__ z8,
                                             float* __restrict__ pp,
                                             float* __restrict__ ap,
                                             float* __restrict__ denom,
                                             float* __restrict__ uacc) {
  const int r = blockIdx.x;
  const int t = threadIdx.x;
  const int lane = t & 63, w = t >> 6;
  __shared__ float red0[4], red1[4];

  if (t < 2) denom[r * 2 + t] = 0.0f;
  if (r < 64 && t < 2) uacc[t * 64 + r] = 0.0f;

  const float4 a = ((const float4*)(p1 + (size_t)r * DDIM))[t];
  const float4 b = ((const float4*)(p2 + (size_t)r * DDIM))[t];
  float s1 = a.x*a.x + a.y*a.y + a.z*a.z + a.w*a.w;
  float s2 = b.x*b.x + b.y*b.y + b.z*b.z + b.w*b.w;
  for (int off = 1; off < 64; off <<= 1) { s1 += __shfl_xor(s1, off); s2 += __shfl_xor(s2, off); }
  if (lane == 0) { red0[w] = s1; red1[w] = s2; }
  __syncthreads();
  const float S1 = red0[0] + red0[1] + red0[2] + red0[3];
  const float S2 = red1[0] + red1[1] + red1[2] + red1[3];
  const float r1 = 1.0f / sqrtf(S1);
  const float r2 = 1.0f / sqrtf(S2);
  const float n1x = a.x*r1, n1y = a.y*r1, n1z = a.z*r1, n1w = a.w*r1;
  const float n2x = b.x*r2, n2y = b.y*r2, n2z = b.z*r2, n2w = b.w*r2;
  float pos = n1x*n2x + n1y*n2y + n1z*n2z + n1w*n2w;
  float al  = (n1x-n2x)*(n1x-n2x) + (n1y-n2y)*(n1y-n2y)
            + (n1z-n2z)*(n1z-n2z) + (n1w-n2w)*(n1w-n2w);
  __syncthreads();
  for (int off = 1; off < 64; off <<= 1) { pos += __shfl_xor(pos, off); al += __shfl_xor(al, off); }
  if (lane == 0) { red0[w] = pos; red1[w] = al; }
  __syncthreads();
  if (t == 0) {
    pp[r] = red0[0] + red0[1] + red0[2] + red0[3];
    ap[r] = red1[0] + red1[1] + red1[2] + red1[3];
  }
  // thread t holds k = 4t..4t+3. group g=t>>4, chunk c=(t>>1)&7, half h=t&1;
  // stored position sp = c<4 ? 2c : 2(c-4)+1
  const int g = t >> 4, c = (t >> 1) & 7, h = t & 1;
  const int sp = (c < 4) ? (2 * c) : (2 * (c - 4) + 1);
  const int off = g * 64 + sp * 8 + h * 4;
  int w1 = __builtin_amdgcn_cvt_pk_fp8_f32(n1x, n1y, 0, false);
  w1     = __builtin_amdgcn_cvt_pk_fp8_f32(n1z, n1w, w1, true);
  int w2 = __builtin_amdgcn_cvt_pk_fp8_f32(n2x, n2y, 0, false);
  w2     = __builtin_amdgcn_cvt_pk_fp8_f32(n2z, n2w, w2, true);
  *(int*)(z8 + (size_t)r * 1024 + off) = w1;
  *(int*)(z8 + (size_t)(r + N_ROWS) * 1024 + off) = w2;
}

// stage THIS WAVE's fragments for one BK=64 K-tile into its private slot.
// Subtiled-linear layout (R13-proven conflict-free): unit u = 16 rows x 64B;
// LDS byte = u*1024 + lane*16 (linear dest); global src row = base + u*16 +
// (lane&15), k = kt*64 + (lane>>4)*16. A units 0-3, B units 0-3 at +4096.
__device__ __forceinline__ void stageW(const char* zb, int arow0, int bcol0,
                                       int kt, char* slot, int lane) {
  const int kb = kt * 64 + (lane >> 4) * 16;
  const int rowin = lane & 15;
#pragma unroll
  for (int u = 0; u < 4; ++u)
    gload_lds16(zb + (size_t)(arow0 + u * 16 + rowin) * 1024 + kb,
                slot + u * 1024 + lane * 16);
#pragma unroll
  for (int u = 0; u < 4; ++u)
    gload_lds16(zb + (size_t)(bcol0 + u * 16 + rowin) * 1024 + kb,
                slot + 4096 + u * 1024 + lane * 16);
}

// ---------- kernel 2: BARRIER-FREE fused z@z^T in fp8 ----------
// One wave per 64x64 output quadrant; private 2-slot LDS ring; depth-2 counted
// vmcnt(8); zero s_barrier. 10 waves/CU, fully desynced (pure TLP).
// Per K-tile per wave: 8 ds_read_b128 + 32 MFMA + 8 gload_lds16.
__global__ __launch_bounds__(64) void kgemm(const unsigned char* __restrict__ z,
                                            float* __restrict__ denom,
                                            float* __restrict__ uacc) {
  extern __shared__ char lds[];
  const int lane = threadIdx.x & 63;
  const int lr = lane >> 4, lc = lane & 15;
  const char* zb = (const char*)z;
  const float RK10 = 14.426950408889634f;  // 10 * log2(e)
  const float K4   = 5.770780163555856f;   // 4 * log2(e)

  // XCD-bijective chunk (8320 = 8*1040), quadrants of a cell adjacent,
  // then supertile-ordered triangle decode on the cell (R11/R13-proven).
  const int cq = (blockIdx.x & 7) * 1040 + (blockIdx.x >> 3);
  const int cell = cq >> 2, quad = cq & 3;
  const int wsr = quad >> 1, wsc = quad & 1;
  int SI = (int)((sqrtf(16.0f + 128.0f * (float)cell) - 4.0f) * (1.0f / 64.0f));
  while (32 * (SI + 1) * (SI + 1) + 4 * (SI + 1) <= cell) ++SI;
  while (32 * SI * SI + 4 * SI > cell) --SI;
  int rem = cell - (32 * SI * SI + 4 * SI);
  int I, J;
  if (rem < 36) {
    int ii = (int)((sqrtf(8.0f * (float)rem + 1.0f) - 1.0f) * 0.5f);
    while ((ii + 1) * (ii + 2) / 2 <= rem) ++ii;
    while (ii * (ii + 1) / 2 > rem) --ii;
    const int jj = rem - ii * (ii + 1) / 2;
    I = SI * 8 + ii; J = SI * 8 + jj;
  } else {
    const int r2 = rem - 36;
    const int SJ = r2 >> 6, w = r2 & 63;
    I = SI * 8 + (w >> 3); J = SJ * 8 + (w & 7);
  }
  const int rowA0 = I * 128, colB0 = J * 128;
  const int arow0 = rowA0 + wsr * 64, bcol0 = colB0 + wsc * 64;
  // strictly-upper quadrants have no work: exit immediately (no barriers to honor)
  if (bcol0 >= arow0 + 64) return;

  f32x4 acc[4][4] = {};

  // prologue: private double-buffer, tiles 0,1 in flight (16 loads); wait tile 0
  stageW(zb, arow0, bcol0, 0, lds, lane);
  stageW(zb, arow0, bcol0, 1, lds + SLOTW, lane);
  asm volatile("s_waitcnt vmcnt(8)" ::: "memory");

#pragma unroll 1
  for (int t = 0; t < KT; ++t) {
    char* S = lds + (t & 1) * SLOTW;
    // one b128 per frag: low 8B = K-slice 0, high 8B = K-slice 1 (knorm interleave)
    const char* Ab = S + lr * 256 + lc * 16;
    const char* Bb = S + 4096 + lr * 256 + lc * 16;
    i64x2 af[4], bg[4];
#pragma unroll
    for (int m = 0; m < 4; ++m) {
      af[m] = *(const i64x2*)(Ab + m * 1024);
      bg[m] = *(const i64x2*)(Bb + m * 1024);
    }
    __builtin_amdgcn_s_setprio(1);
#pragma unroll
    for (int q = 0; q < 2; ++q)
#pragma unroll
      for (int m = 0; m < 4; ++m)
#pragma unroll
        for (int n = 0; n < 4; ++n)
          acc[m][n] = __builtin_amdgcn_mfma_f32_16x16x32_fp8_fp8(
              af[m][q], bg[n][q], acc[m][n], 0, 0, 0);
    __builtin_amdgcn_s_setprio(0);
    if (t + 2 < KT) {
      // reads of slot t&1 have returned (MFMAs above consumed them; lgkm drained)
      asm volatile("s_waitcnt lgkmcnt(0)" ::: "memory");
      __builtin_amdgcn_sched_barrier(0);
      stageW(zb, arow0, bcol0, t + 2, S, lane);          // overwrite same slot
      asm volatile("s_waitcnt vmcnt(8)" ::: "memory");   // tile t+1 resident
    } else if (t + 1 < KT) {
      asm volatile("s_waitcnt vmcnt(0)" ::: "memory");   // last tile resident
    }
  }

  // ---- epilogue: strict-lower mask, row-sums + col-sums + unif (register-only) ----
  const bool unif = (I < 16) || (I < 32 && J >= 16);
  float cs[4] = {0.0f, 0.0f, 0.0f, 0.0f};
  float u = 0.0f;
#pragma unroll
  for (int m = 0; m < 4; ++m) {
    const int growb = arow0 + m * 16 + lr * 4;
#pragma unroll
    for (int i = 0; i < 4; ++i) {
      const int grow = growb + i;
      float rs = 0.0f;
#pragma unroll
      for (int n = 0; n < 4; ++n) {
        const int gcol = bcol0 + n * 16 + lc;
        const bool incl = (gcol < grow);
        float e = incl ? exp2f(acc[m][n][i] * RK10) : 0.0f;
        rs += e;
        cs[n] += e;
        if (unif) u += incl ? exp2f(acc[m][n][i] * K4 - K4) : 0.0f;
      }
      rs += __shfl_xor(rs, 1); rs += __shfl_xor(rs, 2);
      rs += __shfl_xor(rs, 4); rs += __shfl_xor(rs, 8);
      if (lc == 0 && rs > 0.0f) atomicAdd(&denom[grow], rs);
    }
  }
#pragma unroll
  for (int n = 0; n < 4; ++n) {
    float cv = cs[n];
    cv += __shfl_xor(cv, 16); cv += __shfl_xor(cv, 32);
    if (lr == 0 && cv > 0.0f) atomicAdd(&denom[bcol0 + n * 16 + lc], cv);
  }
  if (unif) {
    for (int off = 1; off < 64; off <<= 1) u += __shfl_xor(u, off);
    if (lane == 0 && u > 0.0f)
      atomicAdd(&uacc[((I < 16) ? 0 : 64) + (blockIdx.x & 63)], 2.0f * u);
  }
}

// ---------- kernel 3: reduce log(denom) + partials + final combine ----------
__global__ __launch_bounds__(1024) void klogf(const float* __restrict__ denom,
                                              const float* __restrict__ pp,
                                              const float* __restrict__ ap,
                                              const float* __restrict__ uacc,
                                              float* __restrict__ out) {
  __shared__ float redl[16], redp[16], reda[16], ured[2];
  const int tid = threadIdx.x;
  float s = 0.0f, sp = 0.0f, sa = 0.0f;
#pragma unroll
  for (int q = 0; q < 8; ++q) s += logf(denom[q * 1024 + tid]);
#pragma unroll
  for (int q = 0; q < 4; ++q) { sp += pp[q * 1024 + tid]; sa += ap[q * 1024 + tid]; }
  const int lane = tid & 63, w = tid >> 6;
  for (int off = 1; off < 64; off <<= 1) {
    s += __shfl_xor(s, off); sp += __shfl_xor(sp, off); sa += __shfl_xor(sa, off);
  }
  if (lane == 0) { redl[w] = s; redp[w] = sp; reda[w] = sa; }
  if (tid < 64) {
    float u0 = uacc[tid], u1 = uacc[64 + tid];
    for (int off = 1; off < 64; off <<= 1) { u0 += __shfl_xor(u0, off); u1 += __shfl_xor(u1, off); }
    if (tid == 0) { ured[0] = u0; ured[1] = u1; }
  }
  __syncthreads();
  if (tid == 0) {
    float S = 0.0f, SP = 0.0f, SA = 0.0f;
#pragma unroll
    for (int i = 0; i < 16; ++i) { S += redl[i]; SP += redp[i]; SA += reda[i]; }
    const float P = 2048.0f * 2047.0f * 0.5f;
    out[0] = (S - 20.0f * SP) / 8192.0f;    // (sum log d - 2*sum_pos/t) / 2n
    out[1] = SA / 4096.0f;                  // lalign
    out[2] = 0.5f * (logf(ured[0] * 0.5f / P) + logf(ured[1] * 0.5f / P));
  }
}

extern "C" void kernel_launch(void* const* d_in, const int* in_sizes, int n_in,
                              void* d_out, int out_size, void* d_ws, size_t ws_size,
                              hipStream_t stream) {
  const float* p1 = (const float*)d_in[0];
  const float* p2 = (const float*)d_in[1];
  float* out = (float*)d_out;
  char* ws = (char*)d_ws;
  unsigned char* z8 = (unsigned char*)ws;                     // 8192 x 1024 fp8 = 8 MB
  float* denom = (float*)(ws + (size_t)M_TOT * DDIM);         // 8192 f32
  float* uacc  = denom + M_TOT;                               // 128 f32 spread unif acc
  float* pp    = uacc + 128;                                  // 4096 pos partials
  float* ap    = pp + 4096;                                   // 4096 align partials

  (void)hipFuncSetAttribute((const void*)kgemm,
                            hipFuncAttributeMaxDynamicSharedMemorySize, LDS_TOTAL);
  knorm<<<N_ROWS, 256, 0, stream>>>(p1, p2, z8, pp, ap, denom, uacc);
  kgemm<<<NQUAD, 64, LDS_TOTAL, stream>>>(z8, denom, uacc);
  klogf<<<1, 1024, 0, stream>>>(denom, pp, ap, uacc, out);
}

// Round 19
// 92.319 us; speedup vs baseline: 1.5601x; 1.5601x over previous
//
#include <hip/hip_runtime.h>
#include <stdint.h>

#define DDIM   1024
#define M_TOT  8192
#define N_ROWS 4096
#define KT     16              // 1024 / BK=64 (fp8: 64 B per row per K-tile)
#define NCELL  2080            // 128x128 cells, 64x64 grid lower triangle J<=I
#define SLOT   16384           // A 128x64 fp8 (8KB) + B 128x64 fp8 (8KB)
#define NSLOT  3
#define LDS_TOTAL (NSLOT * SLOT)   // 49152 -> 3 blocks/CU

typedef __attribute__((ext_vector_type(4))) float f32x4;
typedef __attribute__((ext_vector_type(2))) long i64x2;

__device__ __forceinline__ void gload_lds16(const void* g, void* l) {
  __builtin_amdgcn_global_load_lds(
      (const __attribute__((address_space(1))) uint32_t*)g,
      (__attribute__((address_space(3))) uint32_t*)l, 16, 0, 0);
}

// ---------- kernel 1: row-normalize, emit PERMUTED fp8 z, per-row pos/align partials ----------
// z8 row = 1024 fp8 bytes. Within each 64-B K-group, 8-byte chunks stored in order
// [c0,c4,c1,c5,c2,c6,c3,c7] so one ds_read_b128 in kgemm yields both K=32 MFMA frags
// per lane. Permutation is shared by A and B reads -> dot products unaffected.
// Also zeroes denom/uacc (folded from the old memset launch; disjoint stores,
// ordered by the kernel boundary before kgemm).
__global__ __launch_bounds__(256) void knorm(const float* __restrict__ p1,
                                             const float* __restrict__ p2,
                                             unsigned char* __restrict__ z8,
                                             float* __restrict__ pp,
                                             float* __restrict__ ap,
                                             float* __restrict__ denom,
                                             float* __restrict__ uacc) {
  const int r = blockIdx.x;
  const int t = threadIdx.x;
  const int lane = t & 63, w = t >> 6;
  __shared__ float red0[4], red1[4];

  if (t < 2) denom[r * 2 + t] = 0.0f;
  if (r < 64 && t < 2) uacc[t * 64 + r] = 0.0f;

  const float4 a = ((const float4*)(p1 + (size_t)r * DDIM))[t];
  const float4 b = ((const float4*)(p2 + (size_t)r * DDIM))[t];
  float s1 = a.x*a.x + a.y*a.y + a.z*a.z + a.w*a.w;
  float s2 = b.x*b.x + b.y*b.y + b.z*b.z + b.w*b.w;
  for (int off = 1; off < 64; off <<= 1) { s1 += __shfl_xor(s1, off); s2 += __shfl_xor(s2, off); }
  if (lane == 0) { red0[w] = s1; red1[w] = s2; }
  __syncthreads();
  const float S1 = red0[0] + red0[1] + red0[2] + red0[3];
  const float S2 = red1[0] + red1[1] + red1[2] + red1[3];
  const float r1 = 1.0f / sqrtf(S1);
  const float r2 = 1.0f / sqrtf(S2);
  const float n1x = a.x*r1, n1y = a.y*r1, n1z = a.z*r1, n1w = a.w*r1;
  const float n2x = b.x*r2, n2y = b.y*r2, n2z = b.z*r2, n2w = b.w*r2;
  float pos = n1x*n2x + n1y*n2y + n1z*n2z + n1w*n2w;
  float al  = (n1x-n2x)*(n1x-n2x) + (n1y-n2y)*(n1y-n2y)
            + (n1z-n2z)*(n1z-n2z) + (n1w-n2w)*(n1w-n2w);
  __syncthreads();
  for (int off = 1; off < 64; off <<= 1) { pos += __shfl_xor(pos, off); al += __shfl_xor(al, off); }
  if (lane == 0) { red0[w] = pos; red1[w] = al; }
  __syncthreads();
  if (t == 0) {
    pp[r] = red0[0] + red0[1] + red0[2] + red0[3];
    ap[r] = red1[0] + red1[1] + red1[2] + red1[3];
  }
  // thread t holds k = 4t..4t+3. group g=t>>4, chunk c=(t>>1)&7, half h=t&1;
  // stored position sp = c<4 ? 2c : 2(c-4)+1
  const int g = t >> 4, c = (t >> 1) & 7, h = t & 1;
  const int sp = (c < 4) ? (2 * c) : (2 * (c - 4) + 1);
  const int off = g * 64 + sp * 8 + h * 4;
  int w1 = __builtin_amdgcn_cvt_pk_fp8_f32(n1x, n1y, 0, false);
  w1     = __builtin_amdgcn_cvt_pk_fp8_f32(n1z, n1w, w1, true);
  int w2 = __builtin_amdgcn_cvt_pk_fp8_f32(n2x, n2y, 0, false);
  w2     = __builtin_amdgcn_cvt_pk_fp8_f32(n2z, n2w, w2, true);
  *(int*)(z8 + (size_t)r * 1024 + off) = w1;
  *(int*)(z8 + (size_t)(r + N_ROWS) * 1024 + off) = w2;
}

// stage one BK=64 K-tile (fp8), subtiled-linear layout (R13-proven conflict-free):
// slot byte = unit*1024 + p*256 + rowin*16 (p = 16B granule = stored chunks {2p,2p+1}).
// A units 0-7, B at +8192. gload dest = wave-uniform + lane*16 (HW); row stride 1024 B.
__device__ __forceinline__ void stage64(const char* zb, int rowA0, int colB0,
                                        int kt, char* slot, int wid, int lane) {
  const int kb = kt * 64 + (lane >> 4) * 16;   // granule p = lane>>4
  const int rowin = lane & 15;
  const int u0 = wid * 2, u1 = wid * 2 + 1;
  gload_lds16(zb + (size_t)(rowA0 + u0 * 16 + rowin) * 1024 + kb, slot + u0 * 1024 + lane * 16);
  gload_lds16(zb + (size_t)(rowA0 + u1 * 16 + rowin) * 1024 + kb, slot + u1 * 1024 + lane * 16);
  gload_lds16(zb + (size_t)(colB0 + u0 * 16 + rowin) * 1024 + kb, slot + 8192 + u0 * 1024 + lane * 16);
  gload_lds16(zb + (size_t)(colB0 + u1 * 16 + rowin) * 1024 + kb, slot + 8192 + u1 * 1024 + lane * 16);
}

// ---------- kernel 2: fused z@z^T in fp8, 128x128 cells, 3-slot ring, counted vmcnt ----------
// Per barrier-pair: 8 ds_read_b128 + 32 MFMA(16x16x32 fp8) per wave. 3 blocks/CU.
// Cell order: 8x8 supertiles + XCD-bijective chunking (R11/R12-proven).
__global__ __launch_bounds__(256, 3) void kgemm(const unsigned char* __restrict__ z,
                                                float* __restrict__ denom,
                                                float* __restrict__ uacc) {
  extern __shared__ char lds[];
  const int tid  = threadIdx.x;
  const int lane = tid & 63, wid = tid >> 6;
  const int wsr  = wid >> 1, wsc = wid & 1;   // 2x2 waves, wave tile 64x64
  const int lr = lane >> 4, lc = lane & 15;
  const char* zb = (const char*)z;
  const float RK10 = 14.426950408889634f;  // 10 * log2(e)
  const float K4   = 5.770780163555856f;   // 4 * log2(e)

  // XCD-bijective chunk, then supertile-ordered triangle decode (R11-proven).
  const int cdx = (blockIdx.x & 7) * 260 + (blockIdx.x >> 3);
  int SI = (int)((sqrtf(16.0f + 128.0f * (float)cdx) - 4.0f) * (1.0f / 64.0f));
  while (32 * (SI + 1) * (SI + 1) + 4 * (SI + 1) <= cdx) ++SI;
  while (32 * SI * SI + 4 * SI > cdx) --SI;
  int rem = cdx - (32 * SI * SI + 4 * SI);
  int I, J;
  if (rem < 36) {
    int ii = (int)((sqrtf(8.0f * (float)rem + 1.0f) - 1.0f) * 0.5f);
    while ((ii + 1) * (ii + 2) / 2 <= rem) ++ii;
    while (ii * (ii + 1) / 2 > rem) --ii;
    const int jj = rem - ii * (ii + 1) / 2;
    I = SI * 8 + ii; J = SI * 8 + jj;
  } else {
    const int r2 = rem - 36;
    const int SJ = r2 >> 6, w = r2 & 63;
    I = SI * 8 + (w >> 3); J = SJ * 8 + (w & 7);
  }
  const int rowA0 = I * 128, colB0 = J * 128;
  const bool useful = (colB0 + wsc * 64) < (rowA0 + wsr * 64 + 64);

  f32x4 acc[4][4] = {};

  // prologue: tiles 0,1 in flight (8 gload instr/thread); wait tile 0 (8->4)
  stage64(zb, rowA0, colB0, 0, lds, wid, lane);
  stage64(zb, rowA0, colB0, 1, lds + SLOT, wid, lane);
  asm volatile("s_waitcnt vmcnt(4)" ::: "memory");
  __builtin_amdgcn_s_barrier();
  __builtin_amdgcn_sched_barrier(0);

#pragma unroll 1
  for (int t = 0; t < KT; ++t) {
    if (t + 2 < KT)
      stage64(zb, rowA0, colB0, t + 2, lds + ((t + 2) % 3) * SLOT, wid, lane);
    __builtin_amdgcn_sched_barrier(0);
    const char* S = lds + (t % 3) * SLOT;
    if (useful) {
      // one b128 per frag: low 8B = K-slice 0, high 8B = K-slice 1 (knorm interleave)
      const char* Ab = S + wsr * 4096 + lr * 256 + lc * 16;
      const char* Bb = S + 8192 + wsc * 4096 + lr * 256 + lc * 16;
      i64x2 af[4], bg[4];
#pragma unroll
      for (int m = 0; m < 4; ++m) {
        af[m] = *(const i64x2*)(Ab + m * 1024);
        bg[m] = *(const i64x2*)(Bb + m * 1024);
      }
      __builtin_amdgcn_s_setprio(1);
#pragma unroll
      for (int q = 0; q < 2; ++q)
#pragma unroll
        for (int m = 0; m < 4; ++m)
#pragma unroll
          for (int n = 0; n < 4; ++n)
            acc[m][n] = __builtin_amdgcn_mfma_f32_16x16x32_fp8_fp8(
                af[m][q], bg[n][q], acc[m][n], 0, 0, 0);
      __builtin_amdgcn_s_setprio(0);
    }
    if (t + 2 < KT) asm volatile("s_waitcnt vmcnt(4)" ::: "memory");
    else            asm volatile("s_waitcnt vmcnt(0)" ::: "memory");
    __builtin_amdgcn_s_barrier();
    __builtin_amdgcn_sched_barrier(0);
  }

  // ---- epilogue: strict-lower mask, row-sums + col-sums + unif (register-only) ----
  const bool unif = (I < 16) || (I < 32 && J >= 16);
  if (useful) {
    float cs[4] = {0.0f, 0.0f, 0.0f, 0.0f};
    float u = 0.0f;
#pragma unroll
    for (int m = 0; m < 4; ++m) {
      const int growb = rowA0 + wsr * 64 + m * 16 + lr * 4;
#pragma unroll
      for (int i = 0; i < 4; ++i) {
        const int grow = growb + i;
        float rs = 0.0f;
#pragma unroll
        for (int n = 0; n < 4; ++n) {
          const int gcol = colB0 + wsc * 64 + n * 16 + lc;
          const bool incl = (gcol < grow);
          float e = incl ? exp2f(acc[m][n][i] * RK10) : 0.0f;
          rs += e;
          cs[n] += e;
          if (unif) u += incl ? exp2f(acc[m][n][i] * K4 - K4) : 0.0f;
        }
        rs += __shfl_xor(rs, 1); rs += __shfl_xor(rs, 2);
        rs += __shfl_xor(rs, 4); rs += __shfl_xor(rs, 8);
        if (lc == 0 && rs > 0.0f) atomicAdd(&denom[grow], rs);
      }
    }
#pragma unroll
    for (int n = 0; n < 4; ++n) {
      float cv = cs[n];
      cv += __shfl_xor(cv, 16); cv += __shfl_xor(cv, 32);
      if (lr == 0 && cv > 0.0f) atomicAdd(&denom[colB0 + wsc * 64 + n * 16 + lc], cv);
    }
    if (unif) {
      for (int off = 1; off < 64; off <<= 1) u += __shfl_xor(u, off);
      if (lane == 0 && u > 0.0f)
        atomicAdd(&uacc[((I < 16) ? 0 : 64) + (blockIdx.x & 63)], 2.0f * u);
    }
  }
}

// ---------- kernel 3: reduce log(denom) + partials + final combine ----------
__global__ __launch_bounds__(1024) void klogf(const float* __restrict__ denom,
                                              const float* __restrict__ pp,
                                              const float* __restrict__ ap,
                                              const float* __restrict__ uacc,
                                              float* __restrict__ out) {
  __shared__ float redl[16], redp[16], reda[16], ured[2];
  const int tid = threadIdx.x;
  float s = 0.0f, sp = 0.0f, sa = 0.0f;
#pragma unroll
  for (int q = 0; q < 8; ++q) s += logf(denom[q * 1024 + tid]);
#pragma unroll
  for (int q = 0; q < 4; ++q) { sp += pp[q * 1024 + tid]; sa += ap[q * 1024 + tid]; }
  const int lane = tid & 63, w = tid >> 6;
  for (int off = 1; off < 64; off <<= 1) {
    s += __shfl_xor(s, off); sp += __shfl_xor(sp, off); sa += __shfl_xor(sa, off);
  }
  if (lane == 0) { redl[w] = s; redp[w] = sp; reda[w] = sa; }
  if (tid < 64) {
    float u0 = uacc[tid], u1 = uacc[64 + tid];
    for (int off = 1; off < 64; off <<= 1) { u0 += __shfl_xor(u0, off); u1 += __shfl_xor(u1, off); }
    if (tid == 0) { ured[0] = u0; ured[1] = u1; }
  }
  __syncthreads();
  if (tid == 0) {
    float S = 0.0f, SP = 0.0f, SA = 0.0f;
#pragma unroll
    for (int i = 0; i < 16; ++i) { S += redl[i]; SP += redp[i]; SA += reda[i]; }
    const float P = 2048.0f * 2047.0f * 0.5f;
    out[0] = (S - 20.0f * SP) / 8192.0f;    // (sum log d - 2*sum_pos/t) / 2n
    out[1] = SA / 4096.0f;                  // lalign
    out[2] = 0.5f * (logf(ured[0] * 0.5f / P) + logf(ured[1] * 0.5f / P));
  }
}

extern "C" void kernel_launch(void* const* d_in, const int* in_sizes, int n_in,
                              void* d_out, int out_size, void* d_ws, size_t ws_size,
                              hipStream_t stream) {
  const float* p1 = (const float*)d_in[0];
  const float* p2 = (const float*)d_in[1];
  float* out = (float*)d_out;
  char* ws = (char*)d_ws;
  unsigned char* z8 = (unsigned char*)ws;                     // 8192 x 1024 fp8 = 8 MB
  float* denom = (float*)(ws + (size_t)M_TOT * DDIM);         // 8192 f32
  float* uacc  = denom + M_TOT;                               // 128 f32 spread unif acc
  float* pp    = uacc + 128;                                  // 4096 pos partials
  float* ap    = pp + 4096;                                   // 4096 align partials

  (void)hipFuncSetAttribute((const void*)kgemm,
                            hipFuncAttributeMaxDynamicSharedMemorySize, LDS_TOTAL);
  knorm<<<N_ROWS, 256, 0, stream>>>(p1, p2, z8, pp, ap, denom, uacc);
  kgemm<<<NCELL, 256, LDS_TOTAL, stream>>>(z8, denom, uacc);
  klogf<<<1, 1024, 0, stream>>>(denom, pp, ap, uacc, out);
}